// Round 9
// baseline (197.253 us; speedup 1.0000x reference)
//
#include <hip/hip_runtime.h>
#include <hip/hip_bf16.h>
#include <stdint.h>

#define DEVINL __device__ __forceinline__

typedef __attribute__((ext_vector_type(4))) float f32x4;
typedef __attribute__((ext_vector_type(8))) __bf16 bfv8;
typedef __attribute__((ext_vector_type(8))) short s16x8;
typedef __attribute__((ext_vector_type(4))) short s16x4;

// ---- helpers ----
DEVINL short f2bf(float f) {  // fp32 -> bf16 bits, RTNE
  union { float f; unsigned u; } v; v.f = f;
  unsigned r = v.u + 0x7FFFu + ((v.u >> 16) & 1u);
  return (short)(r >> 16);
}
DEVINL float bf2f(short h) {
  union { unsigned u; float f; } v; v.u = ((unsigned)(unsigned short)h) << 16;
  return v.f;
}
DEVINL void gload_lds16(const void* g, void* l) {
  // 16B direct global->LDS. LDS dest = wave-uniform base + lane*16.
  __builtin_amdgcn_global_load_lds((__attribute__((address_space(1))) unsigned*)(g),
                                   (__attribute__((address_space(3))) unsigned*)(l),
                                   16, 0, 0);
}
#define S_BARRIER() __builtin_amdgcn_s_barrier()
#define MEMORD() asm volatile("" ::: "memory")
template <int N> DEVINL void vmwaitc() {
  asm volatile("s_waitcnt vmcnt(%0)" :: "i"(N) : "memory");
}
// bijective XCD swizzle (n % 8 == 0): consecutive output slots cluster per XCD
DEVINL int xswz(int p, int n) { return (p & 7) * (n >> 3) + (p >> 3); }

// ======== 256(M) x (4*NF*16)(N) tile, BK=32, RING-slot LDS ring, READ-AHEAD core ========
// 512 threads = 8 waves (2M x 4N); wave tile 128 x (NF*16).
// Slot layout (shorts): A [256][32] = 8192, then B [BU*128][32] = BU*4096.
// READ-AHEAD pipeline: each phase issues ds_reads for the NEXT MFMA cluster, then runs
// MFMA on regs loaded the previous phase (reads overlap MFMA; compiler handles lgkm deps).
// Phase layout per K-tile (2 phases, 2 barriers):
//   q0: stage A(kt+2) | read aB=A1(kt)             | MFMA(aA,bA) | vmcnt | BAR
//   q1: stage B(kt+2) | read aA=A0(kt+1),bB=B(kt+1)| MFMA(aB,bA) |         BAR
// Hazards: stage of kt+2 -> slot (kt-1)%RING whose last reads ended >=2 barriers earlier
// (no WAR). vmcnt(2): only STAGE_A (2 loads) is issued between tile kt+1's last load and
// this wait -> tile kt+1 fully landed; the following BAR makes it globally visible.
// Holds for ANY BU. Bank swizzle: storage chunk = logical chunk ^ ((row>>1)&3),
// inverse-swizzled GLOBAL source + swizzled ds_read. Verified 0 conflicts (r2/r3/r6/r7).
template <int BU, int NF, int RING>
DEVINL void gemm_core(const short* __restrict__ Ag, const short* __restrict__ Bg,
                      int lda, int ldb, int m0, int n0, int nkt,
                      short* lds, f32x4 (&acc)[8][NF]) {
  constexpr int U = 2 + BU;              // loads per K-tile
  constexpr int SLOT = 8192 + BU * 4096; // shorts per ring slot
  const int tid = threadIdx.x;
  const int w = tid >> 6, l = tid & 63;
  const int wm = w >> 2, wn = w & 3;
  const int lr = l & 15, lg = l >> 4;
  const int stg_row = w * 16 + (l >> 2);
  const int stg_col = (((l & 3) ^ ((l >> 3) & 3)) << 3);   // inverse-swizzled source col
  const int ck = ((lg ^ ((lr >> 1) & 3)) << 3);            // swizzled read chunk
  const int aro = (wm * 128 + lr) * 32 + ck;               // + 2048 for A1-half, + mf*512
  const int bro = 8192 + (wn * (NF * 16) + lr) * 32 + ck;  // + nf*512
  const int dW = w * 512;                                  // wave-uniform LDS dest

#define STAGE_A(t) { short* S_ = lds + ((t) % RING) * SLOT;                                \
    gload_lds16(Ag + (size_t)(m0 + stg_row) * lda + (t) * 32 + stg_col, S_ + dW);          \
    gload_lds16(Ag + (size_t)(m0 + 128 + stg_row) * lda + (t) * 32 + stg_col,              \
                S_ + 4096 + dW); }
#define STAGE_B(t) { short* S_ = lds + ((t) % RING) * SLOT;                                \
    _Pragma("unroll")                                                                      \
    for (int u_ = 0; u_ < BU; ++u_)                                                        \
      gload_lds16(Bg + (size_t)(n0 + u_ * 128 + stg_row) * ldb + (t) * 32 + stg_col,       \
                  S_ + 8192 + u_ * 4096 + dW); }

  // ---- prologue: stage tiles 0..RING-2; wait tile0; barrier; preload tile0 regs ----
#pragma unroll
  for (int t = 0; t < RING - 1; ++t) { STAGE_A(t); STAGE_B(t); }
  vmwaitc<(RING - 2) * U>(); S_BARRIER(); MEMORD();

  bfv8 aA[4], aB[4], bA[NF], bB[NF];
  {
    const short* Sp = lds;  // slot 0
#pragma unroll
    for (int mf = 0; mf < 4; ++mf) aA[mf] = *(const bfv8*)(Sp + aro + mf * 512);
#pragma unroll
    for (int nf = 0; nf < NF; ++nf) bA[nf] = *(const bfv8*)(Sp + bro + nf * 512);
  }

#pragma unroll 1
  for (int kt = 0; kt < nkt; kt += 2) {  // nkt even: 2 K-tiles per iteration
    const short* S1 = lds + ((kt + 1) % RING) * SLOT;
    const short* S2 = lds + ((kt + 2) % RING) * SLOT;
    const short* S0 = lds + (kt % RING) * SLOT;
    // ---- tile kt, q0 ----
    if (kt + 2 < nkt) STAGE_A(kt + 2);
#pragma unroll
    for (int mf = 0; mf < 4; ++mf) aB[mf] = *(const bfv8*)(S0 + aro + 2048 + mf * 512);
    __builtin_amdgcn_s_setprio(1);
#pragma unroll
    for (int mf = 0; mf < 4; ++mf)
#pragma unroll
      for (int nf = 0; nf < NF; ++nf)
        acc[mf][nf] = __builtin_amdgcn_mfma_f32_16x16x32_bf16(aA[mf], bA[nf], acc[mf][nf], 0, 0, 0);
    __builtin_amdgcn_s_setprio(0);
    if (kt + 2 < nkt) vmwaitc<2>(); else vmwaitc<0>();
    S_BARRIER(); MEMORD();
    // ---- tile kt, q1 ----
    if (kt + 2 < nkt) STAGE_B(kt + 2);
#pragma unroll
    for (int mf = 0; mf < 4; ++mf) aA[mf] = *(const bfv8*)(S1 + aro + mf * 512);
#pragma unroll
    for (int nf = 0; nf < NF; ++nf) bB[nf] = *(const bfv8*)(S1 + bro + nf * 512);
    __builtin_amdgcn_s_setprio(1);
#pragma unroll
    for (int mf = 0; mf < 4; ++mf)
#pragma unroll
      for (int nf = 0; nf < NF; ++nf)
        acc[4 + mf][nf] = __builtin_amdgcn_mfma_f32_16x16x32_bf16(aB[mf], bA[nf], acc[4 + mf][nf], 0, 0, 0);
    __builtin_amdgcn_s_setprio(0);
    S_BARRIER(); MEMORD();
    // ---- tile kt+1, q0 ----
    if (kt + 3 < nkt) STAGE_A(kt + 3);
#pragma unroll
    for (int mf = 0; mf < 4; ++mf) aB[mf] = *(const bfv8*)(S1 + aro + 2048 + mf * 512);
    __builtin_amdgcn_s_setprio(1);
#pragma unroll
    for (int mf = 0; mf < 4; ++mf)
#pragma unroll
      for (int nf = 0; nf < NF; ++nf)
        acc[mf][nf] = __builtin_amdgcn_mfma_f32_16x16x32_bf16(aA[mf], bB[nf], acc[mf][nf], 0, 0, 0);
    __builtin_amdgcn_s_setprio(0);
    if (kt + 3 < nkt) vmwaitc<2>(); else vmwaitc<0>();
    S_BARRIER(); MEMORD();
    // ---- tile kt+1, q1 ----
    if (kt + 3 < nkt) STAGE_B(kt + 3);
    if (kt + 2 < nkt) {
#pragma unroll
      for (int mf = 0; mf < 4; ++mf) aA[mf] = *(const bfv8*)(S2 + aro + mf * 512);
#pragma unroll
      for (int nf = 0; nf < NF; ++nf) bA[nf] = *(const bfv8*)(S2 + bro + nf * 512);
    }
    __builtin_amdgcn_s_setprio(1);
#pragma unroll
    for (int mf = 0; mf < 4; ++mf)
#pragma unroll
      for (int nf = 0; nf < NF; ++nf)
        acc[4 + mf][nf] = __builtin_amdgcn_mfma_f32_16x16x32_bf16(aB[mf], bB[nf], acc[4 + mf][nf], 0, 0, 0);
    __builtin_amdgcn_s_setprio(0);
    S_BARRIER(); MEMORD();
  }
#undef STAGE_A
#undef STAGE_B
}

// ============ prep: cast fp32->bf16 (Q,V) fused with W transpose+cast ============
__global__ __launch_bounds__(256) void prep_kernel(
    const float* __restrict__ q, const float* __restrict__ v,
    const float* __restrict__ Wq, const float* __restrict__ Wk, const float* __restrict__ Wv,
    short* __restrict__ Qc, short* __restrict__ Vc,
    short* __restrict__ WTq, short* __restrict__ WTk, short* __restrict__ WTv) {
  __shared__ float tile[64][65];
  const int bx = blockIdx.x;
  if (bx < 8192) {
    const float* src = (bx < 4096) ? q : v;
    short* dst = (bx < 4096) ? Qc : Vc;
    const size_t i = ((size_t)(bx & 4095) * 256 + threadIdx.x) * 8;
    f32x4 x0 = *(const f32x4*)(src + i);
    f32x4 x1 = *(const f32x4*)(src + i + 4);
    s16x8 o;
#pragma unroll
    for (int j = 0; j < 4; ++j) { o[j] = f2bf(x0[j]); o[4 + j] = f2bf(x1[j]); }
    *(s16x8*)(dst + i) = o;
  } else {
    const int z = (bx - 8192) >> 8, xx = (bx - 8192) & 255;
    const float* W = (z == 0) ? Wq : (z == 1) ? Wk : Wv;
    short* WT = (z == 0) ? WTq : (z == 1) ? WTk : WTv;
    const int k0 = (xx & 15) << 6, n0 = (xx >> 4) << 6;
    const int c = threadIdx.x & 63, r0 = threadIdx.x >> 6;
#pragma unroll
    for (int i = 0; i < 16; ++i) {
      int r = (i << 2) + r0;
      tile[r][c] = W[(size_t)(k0 + r) * 1024 + n0 + c];
    }
    __syncthreads();
#pragma unroll
    for (int i = 0; i < 16; ++i) {
      int a = (i << 2) + r0;
      WT[(size_t)(n0 + a) * 1024 + k0 + c] = f2bf(tile[c][a]);
    }
  }
}

// ==== Q+K projections: tile 256x256, grid 256 (2 sel x 32 bm x 4 bn), ring-3, 1/CU ====
__global__ __launch_bounds__(512, 2) void qkproj_kernel(
    const short* __restrict__ Qc, const short* __restrict__ Vc,
    const short* __restrict__ WTq, const short* __restrict__ WTk,
    const float* __restrict__ bq, const float* __restrict__ bk,
    short* __restrict__ Qb, short* __restrict__ Kb) {
  __shared__ short lds[49152];  // 96 KB: 3 x 16384-short slots
  const int o = xswz(blockIdx.x, 256);
  const int sel = o >> 7, r = o & 127;
  const int bm = r >> 2, bn = r & 3;          // bm:[0,32) bn:[0,4)
  const short* A = sel ? Vc : Qc;
  const short* BT = sel ? WTk : WTq;
  const float* bias = sel ? bk : bq;
  short* O = sel ? Kb : Qb;
  const int m0 = bm * 256, n0 = bn * 256;
  f32x4 acc[8][4];
#pragma unroll
  for (int i = 0; i < 8; ++i)
#pragma unroll
    for (int j = 0; j < 4; ++j) acc[i][j] = (f32x4){0.f, 0.f, 0.f, 0.f};
  gemm_core<2, 4, 3>(A, BT, 1024, 1024, m0, n0, 32, lds, acc);
  const int tid = threadIdx.x;
  const int w = tid >> 6, l = tid & 63;
  const int wm = w >> 2, wn = w & 3, lr = l & 15, lg = l >> 4;
#pragma unroll
  for (int i = 0; i < 8; ++i) {
    const int row0 = m0 + wm * 128 + (i >> 2) * 64 + (i & 3) * 16 + lg * 4;  // <= 8191
#pragma unroll
    for (int nf = 0; nf < 4; ++nf) {
      const int col = n0 + wn * 64 + nf * 16 + lr;  // <= n0+255
      const float bb = bias[col];
#pragma unroll
      for (int j = 0; j < 4; ++j)
        O[(size_t)(row0 + j) * 1024 + col] = f2bf(acc[i][nf][j] + bb);
    }
  }
}

// ==== V projection -> VT[b][u][t]: tile 256x128, grid 256 (32 bm x 8 bn), ring-3 ====
__global__ __launch_bounds__(512, 2) void vproj_kernel(
    const short* __restrict__ Vc, const short* __restrict__ WTv,
    const float* __restrict__ bv, short* __restrict__ VT) {
  __shared__ short lds[36864];  // 72 KB: ring 3 x 12288; reused as 128x264 transpose buf
  const int o = xswz(blockIdx.x, 256);
  const int bm = o >> 3, bn = o & 7;          // bm:[0,32) bn:[0,8)
  const int m0 = bm * 256, n0 = bn * 128;     // m = t rows, n = u cols
  f32x4 acc[8][2];
#pragma unroll
  for (int i = 0; i < 8; ++i)
#pragma unroll
    for (int j = 0; j < 2; ++j) acc[i][j] = (f32x4){0.f, 0.f, 0.f, 0.f};
  gemm_core<1, 2, 3>(Vc, WTv, 1024, 1024, m0, n0, 32, lds, acc);
  const int tid = threadIdx.x;
  const int w = tid >> 6, l = tid & 63;
  const int wm = w >> 2, wn = w & 3, lr = l & 15, lg = l >> 4;
  __syncthreads();
  short* lt = lds;  // [u_local 0..127][t_local 0..255], stride 264
#pragma unroll
  for (int i = 0; i < 8; ++i) {
    const int tl = wm * 128 + (i >> 2) * 64 + (i & 3) * 16 + lg * 4;
#pragma unroll
    for (int nf = 0; nf < 2; ++nf) {
      const int ul = wn * 32 + nf * 16 + lr;
      const float bb = bv[n0 + ul];
      s16x4 pk;
#pragma unroll
      for (int j = 0; j < 4; ++j) pk[j] = f2bf(acc[i][nf][j] + bb);
      *(s16x4*)&lt[ul * 264 + tl] = pk;
    }
  }
  __syncthreads();
  const int b = m0 >> 11, t0 = m0 & 2047;
#pragma unroll
  for (int it = 0; it < 8; ++it) {
    const int cid = it * 512 + tid;
    const int u = cid >> 5, tc = cid & 31;
    s16x8 v8 = *(const s16x8*)&lt[u * 264 + tc * 8];
    *(s16x8*)(VT + ((size_t)b * 1024 + n0 + u) * 2048 + t0 + tc * 8) = v8;
  }
}

// ==== QK^T: scores=(Q.K)/32; tile 256x256, grid 256 (4 bt x 8 bm x 8 bn), 1/CU ====
__global__ __launch_bounds__(512, 2) void qkt_kernel(const short* __restrict__ Qb,
                                                     const short* __restrict__ Kb,
                                                     short* __restrict__ Sb) {
  __shared__ short lds[49152];  // 96 KB
  const int o = xswz(blockIdx.x, 256);
  const int bt = o >> 6, r = o & 63;          // bt:[0,4)
  const int bm = r >> 3, bn = r & 7;          // bm:[0,8) bn:[0,8)
  const short* A = Qb + (size_t)bt * 2097152;
  const short* B = Kb + (size_t)bt * 2097152;
  short* O = Sb + (size_t)bt * 4194304;
  const int m0 = bm * 256, n0 = bn * 256;
  f32x4 acc[8][4];
#pragma unroll
  for (int i = 0; i < 8; ++i)
#pragma unroll
    for (int j = 0; j < 4; ++j) acc[i][j] = (f32x4){0.f, 0.f, 0.f, 0.f};
  gemm_core<2, 4, 3>(A, B, 1024, 1024, m0, n0, 32, lds, acc);
  const int tid = threadIdx.x;
  const int w = tid >> 6, l = tid & 63;
  const int wm = w >> 2, wn = w & 3, lr = l & 15, lg = l >> 4;
#pragma unroll
  for (int i = 0; i < 8; ++i) {
    const int row0 = m0 + wm * 128 + (i >> 2) * 64 + (i & 3) * 16 + lg * 4;  // <= 2047
#pragma unroll
    for (int nf = 0; nf < 4; ++nf) {
      const int col = n0 + wn * 64 + nf * 16 + lr;  // <= 2047
#pragma unroll
      for (int j = 0; j < 4; ++j)
        O[(size_t)(row0 + j) * 2048 + col] = f2bf(acc[i][nf][j] * 0.03125f);
    }
  }
}

// ==== PV split-K: out = P @ V; tile 256x256, grid 256 (2 kh x 4 bt x 8 bm x 4 bn) ====
// kh=0 -> d_out (write), kh=1 -> partial (write); add_kernel folds.
// K-half = 1024 score-cols -> nkt = 32 (FIXED: was 16, dropped half of each K-half).
__global__ __launch_bounds__(512, 2) void pv_kernel(const short* __restrict__ Sb,
                                                    const short* __restrict__ VT,
                                                    float* __restrict__ Out,
                                                    float* __restrict__ Part) {
  __shared__ short lds[49152];  // 96 KB
  const int o = xswz(blockIdx.x, 256);
  const int kh = o >> 7;                       // [0,2)
  const int bt = (o >> 5) & 3;                 // [0,4)
  const int bm = (o >> 2) & 7, bn = o & 3;     // bm:[0,8) bn:[0,4)
  const short* A = Sb + (size_t)bt * 4194304 + kh * 1024;
  const short* B = VT + (size_t)bt * 2097152 + kh * 1024;
  float* O = (kh ? Part : Out) + (size_t)bt * 2097152;
  const int m0 = bm * 256, n0 = bn * 256;
  f32x4 acc[8][4];
#pragma unroll
  for (int i = 0; i < 8; ++i)
#pragma unroll
    for (int j = 0; j < 4; ++j) acc[i][j] = (f32x4){0.f, 0.f, 0.f, 0.f};
  gemm_core<2, 4, 3>(A, B, 2048, 2048, m0, n0, 32, lds, acc);
  const int l = threadIdx.x & 63, w = threadIdx.x >> 6;
  const int wm = w >> 2, wn = w & 3, lr = l & 15, lg = l >> 4;
#pragma unroll
  for (int i = 0; i < 8; ++i) {
    const int row0 = m0 + wm * 128 + (i >> 2) * 64 + (i & 3) * 16 + lg * 4;  // <= 2047
#pragma unroll
    for (int nf = 0; nf < 4; ++nf) {
      const int col = n0 + wn * 64 + nf * 16 + lr;  // <= 1023
#pragma unroll
      for (int j = 0; j < 4; ++j)
        O[(size_t)(row0 + j) * 1024 + col] = acc[i][nf][j];
    }
  }
}

// ============ add: d_out += partial (8M floats, float4) ============
__global__ __launch_bounds__(256) void add_kernel(float* __restrict__ Out,
                                                  const float* __restrict__ Part) {
  const size_t i = ((size_t)blockIdx.x * 256 + threadIdx.x) * 4;
  f32x4 a = *(const f32x4*)(Out + i);
  f32x4 b = *(const f32x4*)(Part + i);
#pragma unroll
  for (int j = 0; j < 4; ++j) a[j] += b[j];
  *(f32x4*)(Out + i) = a;
}

// ============ Row softmax, in-place on bf16 scores [B*S rows][2048] ============
__global__ __launch_bounds__(256) void softmax_kernel(short* __restrict__ Sb) {
  const size_t row = blockIdx.x;
  short* p = Sb + row * 2048;
  const int tid = threadIdx.x;
  const int w = tid >> 6, l = tid & 63;
  s16x8 v = *(const s16x8*)(p + tid * 8);
  float f[8];
#pragma unroll
  for (int j = 0; j < 8; ++j) f[j] = bf2f(v[j]);
  float m = f[0];
#pragma unroll
  for (int j = 1; j < 8; ++j) m = fmaxf(m, f[j]);
#pragma unroll
  for (int o = 32; o > 0; o >>= 1) m = fmaxf(m, __shfl_xor(m, o, 64));
  __shared__ float redm[4], reds[4];
  if (l == 0) redm[w] = m;
  __syncthreads();
  m = fmaxf(fmaxf(redm[0], redm[1]), fmaxf(redm[2], redm[3]));
  float s = 0.f;
#pragma unroll
  for (int j = 0; j < 8; ++j) { f[j] = __expf(f[j] - m); s += f[j]; }
#pragma unroll
  for (int o = 32; o > 0; o >>= 1) s += __shfl_xor(s, o, 64);
  if (l == 0) reds[w] = s;
  __syncthreads();
  s = reds[0] + reds[1] + reds[2] + reds[3];
  const float inv = 1.f / s;
  s16x8 o8;
#pragma unroll
  for (int j = 0; j < 8; ++j) o8[j] = f2bf(f[j] * inv);
  *(s16x8*)(p + tid * 8) = o8;
}

// ============ launch ============
extern "C" void kernel_launch(void* const* d_in, const int* in_sizes, int n_in,
                              void* d_out, int out_size, void* d_ws, size_t ws_size,
                              hipStream_t stream) {
  const float* query = (const float*)d_in[0];
  const float* value = (const float*)d_in[1];
  const float* Wq = (const float*)d_in[2];
  const float* bq = (const float*)d_in[3];
  const float* Wk = (const float*)d_in[4];
  const float* bk = (const float*)d_in[5];
  const float* Wv = (const float*)d_in[6];
  const float* bv = (const float*)d_in[7];

  // Workspace layout (86 MB total):
  //  0: WTq(2M) 2M: WTk(2M) 4M: WTv(2M)
  //  6M: region X (32MB): Qc@6M(16M), Vc@22M(16M) [projection inputs];
  //      later reused as Sb@6M(32MB) [scores/P] -- lifetimes disjoint (stream-ordered)
  //  38M: Qb(16M) 54M: Kb(16M)  -- dead after qkt; region reused as Part@38M(32MB fp32)
  //  70M: VT(16M)
  char* ws = (char*)d_ws;
  short* WTq = (short*)(ws);
  short* WTk = (short*)(ws + ((size_t)2 << 20));
  short* WTv = (short*)(ws + ((size_t)4 << 20));
  short* Qc  = (short*)(ws + ((size_t)6 << 20));
  short* Vc  = (short*)(ws + ((size_t)22 << 20));
  short* Sb  = (short*)(ws + ((size_t)6 << 20));
  short* Qb  = (short*)(ws + ((size_t)38 << 20));
  short* Kb  = (short*)(ws + ((size_t)54 << 20));
  float* Part = (float*)(ws + ((size_t)38 << 20));
  short* VT  = (short*)(ws + ((size_t)70 << 20));

  prep_kernel<<<dim3(8960), 256, 0, stream>>>(query, value, Wq, Wk, Wv, Qc, Vc, WTq, WTk, WTv);

  qkproj_kernel<<<dim3(256), 512, 0, stream>>>(Qc, Vc, WTq, WTk, bq, bk, Qb, Kb);
  vproj_kernel<<<dim3(256), 512, 0, stream>>>(Vc, WTv, bv, VT);

  // scores[b][s][t] = (Q.K)/32
  qkt_kernel<<<dim3(256), 512, 0, stream>>>(Qb, Kb, Sb);

  softmax_kernel<<<dim3(8192), 256, 0, stream>>>(Sb);

  // out[b][s][u] = P @ V, split-K=2 (Qb/Kb dead -> Part reuses their region)
  pv_kernel<<<dim3(256), 512, 0, stream>>>(Sb, VT, (float*)d_out, Part);
  add_kernel<<<dim3(8192), 256, 0, stream>>>((float*)d_out, Part);
}

// Round 10
// 190.534 us; speedup vs baseline: 1.0353x; 1.0353x over previous
//
#include <hip/hip_runtime.h>
#include <hip/hip_bf16.h>
#include <stdint.h>

#define DEVINL __device__ __forceinline__

typedef __attribute__((ext_vector_type(4))) float f32x4;
typedef __attribute__((ext_vector_type(8))) __bf16 bfv8;
typedef __attribute__((ext_vector_type(8))) short s16x8;
typedef __attribute__((ext_vector_type(4))) short s16x4;

// ---- helpers ----
DEVINL short f2bf(float f) {  // fp32 -> bf16 bits, RTNE
  union { float f; unsigned u; } v; v.f = f;
  unsigned r = v.u + 0x7FFFu + ((v.u >> 16) & 1u);
  return (short)(r >> 16);
}
DEVINL float bf2f(short h) {
  union { unsigned u; float f; } v; v.u = ((unsigned)(unsigned short)h) << 16;
  return v.f;
}
DEVINL void gload_lds16(const void* g, void* l) {
  // 16B direct global->LDS. LDS dest = wave-uniform base + lane*16.
  __builtin_amdgcn_global_load_lds((__attribute__((address_space(1))) unsigned*)(g),
                                   (__attribute__((address_space(3))) unsigned*)(l),
                                   16, 0, 0);
}
#define S_BARRIER() __builtin_amdgcn_s_barrier()
#define MEMORD() asm volatile("" ::: "memory")
template <int N> DEVINL void vmwaitc() {
  asm volatile("s_waitcnt vmcnt(%0)" :: "i"(N) : "memory");
}
// bijective XCD swizzle (n % 8 == 0): consecutive output slots cluster per XCD
DEVINL int xswz(int p, int n) { return (p & 7) * (n >> 3) + (p >> 3); }

// ============ 256x256 tile, BK=64, 2-slot dbuf, m201-style 4-quadrant-phase core ============
// 512 threads = 8 waves (2M x 4N); wave tile 128x64; acc[8][4] (Mfrag x Nfrag of 16x16).
// LDS: 2 slots x {A[256][64] + B[256][64]} bf16 = 2 x 64KB = 128 KB.
// Per K-tile (BK=64): 4 phases. Phase q: {ds_read A-frags of quadrant q (+all B-frags if q==0)
//   | stage next tile's half (A0+A1 / B0 / B1 in phases 0/1/2; vmcnt(0) in phase 3)
//   | BARRIER | (lgkm drain via SSA) | setprio(1) 16 MFMA setprio(0) | BARRIER}.
// Reads issued BEFORE the barrier, MFMA after -> read latency hides in barrier wait; waves'
// staggered lgkm completion overlaps MFMA with the LDS queue (m201 mechanism).
// Hazards: staging targets the OTHER slot (strict dbuf; its reads finished last tile, before
// a barrier). vmcnt(0) in phase 3 (last stage issued phase 2, ~1 phase earlier -> ~no stall);
// the phase-3 trailing barrier publishes tile kt+1 before any wave reads it.
// Swizzle (128B rows, 8 chunks): storage chunk = logical chunk ^ (row&7); applied as
// inverse-swizzled GLOBAL source + swizzled ds_read. Per-16-lane-group: 2 lanes/bank = free.
DEVINL void gemm64_core(const short* __restrict__ Ag, const short* __restrict__ Bg,
                        int lda, int ldb, int m0, int n0, int nkt,
                        short* lds, f32x4 (&acc)[8][4]) {
  const int tid = threadIdx.x;
  const int w = tid >> 6, l = tid & 63;
  const int wm = w >> 2, wn = w & 3;
  const int lr = l & 15, lg = l >> 4;
  // staging: per gload, wave w writes rows 8w..8w+7 (lane l -> row +(l>>3), chunk l&7)
  const int srow = 8 * w + (l >> 3);
  const int scol = (((l & 7) ^ ((l >> 3) & 7)) << 3);  // inverse-swizzled source col (shorts)
  const int dW = w * 512;                              // wave-uniform dest offset (shorts)
  // fragment reads: addr = row*64 + ((ks*4+lg) ^ (row&7))*8 ; row&7 == lr&7
  const int xk0 = ((lg ^ (lr & 7)) << 3);
  const int xk1 = (((4 + lg) ^ (lr & 7)) << 3);
  const int aoff = (wm * 128 + lr) * 64;               // + mf*1024 + xk
  const int boff = 16384 + (wn * 64 + lr) * 64;        // + nf*1024 + xk

#define SG_A(t, h) { short* S_ = lds + (((t) & 1) ? 32768 : 0) + (h) * 8192;              \
    gload_lds16(Ag + (size_t)(m0 + 128 * (h) + srow) * lda + (t) * 64 + scol, S_ + dW);   \
    gload_lds16(Ag + (size_t)(m0 + 128 * (h) + 64 + srow) * lda + (t) * 64 + scol,        \
                S_ + 4096 + dW); }
#define SG_B(t, h) { short* S_ = lds + (((t) & 1) ? 32768 : 0) + 16384 + (h) * 8192;      \
    gload_lds16(Bg + (size_t)(n0 + 128 * (h) + srow) * ldb + (t) * 64 + scol, S_ + dW);   \
    gload_lds16(Bg + (size_t)(n0 + 128 * (h) + 64 + srow) * ldb + (t) * 64 + scol,        \
                S_ + 4096 + dW); }
#define MFMA_QUAD(M0, M1)                                                                 \
    _Pragma("unroll")                                                                     \
    for (int nf = 0; nf < 4; ++nf) {                                                      \
      acc[M0][nf] = __builtin_amdgcn_mfma_f32_16x16x32_bf16(a00, br[nf][0], acc[M0][nf], 0, 0, 0); \
      acc[M0][nf] = __builtin_amdgcn_mfma_f32_16x16x32_bf16(a01, br[nf][1], acc[M0][nf], 0, 0, 0); \
      acc[M1][nf] = __builtin_amdgcn_mfma_f32_16x16x32_bf16(a10, br[nf][0], acc[M1][nf], 0, 0, 0); \
      acc[M1][nf] = __builtin_amdgcn_mfma_f32_16x16x32_bf16(a11, br[nf][1], acc[M1][nf], 0, 0, 0); \
    }

  // ---- prologue: stage tile 0; drain; publish ----
  SG_A(0, 0); SG_A(0, 1); SG_B(0, 0); SG_B(0, 1);
  vmwaitc<0>(); S_BARRIER(); MEMORD();

#pragma unroll 1
  for (int kt = 0; kt < nkt; ++kt) {
    const short* S = lds + ((kt & 1) ? 32768 : 0);
    const bool pf = (kt + 1 < nkt);
    bfv8 br[4][2];
    // ---------- phase 0: B(all) + A(q0) reads | stage A(kt+1) ----------
#pragma unroll
    for (int nf = 0; nf < 4; ++nf) {
      br[nf][0] = *(const bfv8*)(S + boff + nf * 1024 + xk0);
      br[nf][1] = *(const bfv8*)(S + boff + nf * 1024 + xk1);
    }
    bfv8 a00 = *(const bfv8*)(S + aoff + 0 * 1024 + xk0);
    bfv8 a01 = *(const bfv8*)(S + aoff + 0 * 1024 + xk1);
    bfv8 a10 = *(const bfv8*)(S + aoff + 1 * 1024 + xk0);
    bfv8 a11 = *(const bfv8*)(S + aoff + 1 * 1024 + xk1);
    if (pf) { SG_A(kt + 1, 0); SG_A(kt + 1, 1); }
    S_BARRIER();
    __builtin_amdgcn_s_setprio(1);
    MFMA_QUAD(0, 1);
    __builtin_amdgcn_s_setprio(0);
    S_BARRIER(); MEMORD();
    // ---------- phase 1: A(q1) reads | stage B0(kt+1) ----------
    a00 = *(const bfv8*)(S + aoff + 2 * 1024 + xk0);
    a01 = *(const bfv8*)(S + aoff + 2 * 1024 + xk1);
    a10 = *(const bfv8*)(S + aoff + 3 * 1024 + xk0);
    a11 = *(const bfv8*)(S + aoff + 3 * 1024 + xk1);
    if (pf) SG_B(kt + 1, 0);
    S_BARRIER();
    __builtin_amdgcn_s_setprio(1);
    MFMA_QUAD(2, 3);
    __builtin_amdgcn_s_setprio(0);
    S_BARRIER(); MEMORD();
    // ---------- phase 2: A(q2) reads | stage B1(kt+1) ----------
    a00 = *(const bfv8*)(S + aoff + 4 * 1024 + xk0);
    a01 = *(const bfv8*)(S + aoff + 4 * 1024 + xk1);
    a10 = *(const bfv8*)(S + aoff + 5 * 1024 + xk0);
    a11 = *(const bfv8*)(S + aoff + 5 * 1024 + xk1);
    if (pf) SG_B(kt + 1, 1);
    S_BARRIER();
    __builtin_amdgcn_s_setprio(1);
    MFMA_QUAD(4, 5);
    __builtin_amdgcn_s_setprio(0);
    S_BARRIER(); MEMORD();
    // ---------- phase 3: A(q3) reads | vmcnt(0) (tile kt+1 landed) ----------
    a00 = *(const bfv8*)(S + aoff + 6 * 1024 + xk0);
    a01 = *(const bfv8*)(S + aoff + 6 * 1024 + xk1);
    a10 = *(const bfv8*)(S + aoff + 7 * 1024 + xk0);
    a11 = *(const bfv8*)(S + aoff + 7 * 1024 + xk1);
    if (pf) vmwaitc<0>();
    S_BARRIER();
    __builtin_amdgcn_s_setprio(1);
    MFMA_QUAD(6, 7);
    __builtin_amdgcn_s_setprio(0);
    S_BARRIER(); MEMORD();
  }
#undef SG_A
#undef SG_B
#undef MFMA_QUAD
}

// ======== legacy 256x128 ring-3 core (proven r6-r9) — kept for vproj ========
template <int BU, int NF, int RING>
DEVINL void gemm_core(const short* __restrict__ Ag, const short* __restrict__ Bg,
                      int lda, int ldb, int m0, int n0, int nkt,
                      short* lds, f32x4 (&acc)[8][NF]) {
  constexpr int U = 2 + BU;
  constexpr int SLOT = 8192 + BU * 4096;
  const int tid = threadIdx.x;
  const int w = tid >> 6, l = tid & 63;
  const int wm = w >> 2, wn = w & 3;
  const int lr = l & 15, lg = l >> 4;
  const int stg_row = w * 16 + (l >> 2);
  const int stg_col = (((l & 3) ^ ((l >> 3) & 3)) << 3);
  const int ck = ((lg ^ ((lr >> 1) & 3)) << 3);
  const int aro = (wm * 128 + lr) * 32 + ck;
  const int bro = 8192 + (wn * (NF * 16) + lr) * 32 + ck;
  const int dW = w * 512;
#define STAGE_A(t) { short* S_ = lds + ((t) % RING) * SLOT;                                \
    gload_lds16(Ag + (size_t)(m0 + stg_row) * lda + (t) * 32 + stg_col, S_ + dW);          \
    gload_lds16(Ag + (size_t)(m0 + 128 + stg_row) * lda + (t) * 32 + stg_col,              \
                S_ + 4096 + dW); }
#define STAGE_B(t) { short* S_ = lds + ((t) % RING) * SLOT;                                \
    _Pragma("unroll")                                                                      \
    for (int u_ = 0; u_ < BU; ++u_)                                                        \
      gload_lds16(Bg + (size_t)(n0 + u_ * 128 + stg_row) * ldb + (t) * 32 + stg_col,       \
                  S_ + 8192 + u_ * 4096 + dW); }
#pragma unroll
  for (int t = 0; t < RING - 1; ++t) { STAGE_A(t); STAGE_B(t); }
  vmwaitc<(RING - 2) * U>(); S_BARRIER(); MEMORD();
  bfv8 aA[4], aB[4], bA[NF], bB[NF];
  {
    const short* Sp = lds;
#pragma unroll
    for (int mf = 0; mf < 4; ++mf) aA[mf] = *(const bfv8*)(Sp + aro + mf * 512);
#pragma unroll
    for (int nf = 0; nf < NF; ++nf) bA[nf] = *(const bfv8*)(Sp + bro + nf * 512);
  }
#pragma unroll 1
  for (int kt = 0; kt < nkt; kt += 2) {
    const short* S1 = lds + ((kt + 1) % RING) * SLOT;
    const short* S2 = lds + ((kt + 2) % RING) * SLOT;
    const short* S0 = lds + (kt % RING) * SLOT;
    if (kt + 2 < nkt) STAGE_A(kt + 2);
#pragma unroll
    for (int mf = 0; mf < 4; ++mf) aB[mf] = *(const bfv8*)(S0 + aro + 2048 + mf * 512);
#pragma unroll
    for (int mf = 0; mf < 4; ++mf)
#pragma unroll
      for (int nf = 0; nf < NF; ++nf)
        acc[mf][nf] = __builtin_amdgcn_mfma_f32_16x16x32_bf16(aA[mf], bA[nf], acc[mf][nf], 0, 0, 0);
    if (kt + 2 < nkt) vmwaitc<2>(); else vmwaitc<0>();
    S_BARRIER(); MEMORD();
    if (kt + 2 < nkt) STAGE_B(kt + 2);
#pragma unroll
    for (int mf = 0; mf < 4; ++mf) aA[mf] = *(const bfv8*)(S1 + aro + mf * 512);
#pragma unroll
    for (int nf = 0; nf < NF; ++nf) bB[nf] = *(const bfv8*)(S1 + bro + nf * 512);
#pragma unroll
    for (int mf = 0; mf < 4; ++mf)
#pragma unroll
      for (int nf = 0; nf < NF; ++nf)
        acc[4 + mf][nf] = __builtin_amdgcn_mfma_f32_16x16x32_bf16(aB[mf], bA[nf], acc[4 + mf][nf], 0, 0, 0);
    S_BARRIER(); MEMORD();
    if (kt + 3 < nkt) STAGE_A(kt + 3);
#pragma unroll
    for (int mf = 0; mf < 4; ++mf) aB[mf] = *(const bfv8*)(S1 + aro + 2048 + mf * 512);
#pragma unroll
    for (int mf = 0; mf < 4; ++mf)
#pragma unroll
      for (int nf = 0; nf < NF; ++nf)
        acc[mf][nf] = __builtin_amdgcn_mfma_f32_16x16x32_bf16(aA[mf], bB[nf], acc[mf][nf], 0, 0, 0);
    if (kt + 3 < nkt) vmwaitc<2>(); else vmwaitc<0>();
    S_BARRIER(); MEMORD();
    if (kt + 3 < nkt) STAGE_B(kt + 3);
    if (kt + 2 < nkt) {
#pragma unroll
      for (int mf = 0; mf < 4; ++mf) aA[mf] = *(const bfv8*)(S2 + aro + mf * 512);
#pragma unroll
      for (int nf = 0; nf < NF; ++nf) bA[nf] = *(const bfv8*)(S2 + bro + nf * 512);
    }
#pragma unroll
    for (int mf = 0; mf < 4; ++mf)
#pragma unroll
      for (int nf = 0; nf < NF; ++nf)
        acc[4 + mf][nf] = __builtin_amdgcn_mfma_f32_16x16x32_bf16(aB[mf], bB[nf], acc[4 + mf][nf], 0, 0, 0);
    S_BARRIER(); MEMORD();
  }
#undef STAGE_A
#undef STAGE_B
}

// ============ prep: cast fp32->bf16 (Q,V) fused with W transpose+cast ============
__global__ __launch_bounds__(256) void prep_kernel(
    const float* __restrict__ q, const float* __restrict__ v,
    const float* __restrict__ Wq, const float* __restrict__ Wk, const float* __restrict__ Wv,
    short* __restrict__ Qc, short* __restrict__ Vc,
    short* __restrict__ WTq, short* __restrict__ WTk, short* __restrict__ WTv) {
  __shared__ float tile[64][65];
  const int bx = blockIdx.x;
  if (bx < 8192) {
    const float* src = (bx < 4096) ? q : v;
    short* dst = (bx < 4096) ? Qc : Vc;
    const size_t i = ((size_t)(bx & 4095) * 256 + threadIdx.x) * 8;
    f32x4 x0 = *(const f32x4*)(src + i);
    f32x4 x1 = *(const f32x4*)(src + i + 4);
    s16x8 o;
#pragma unroll
    for (int j = 0; j < 4; ++j) { o[j] = f2bf(x0[j]); o[4 + j] = f2bf(x1[j]); }
    *(s16x8*)(dst + i) = o;
  } else {
    const int z = (bx - 8192) >> 8, xx = (bx - 8192) & 255;
    const float* W = (z == 0) ? Wq : (z == 1) ? Wk : Wv;
    short* WT = (z == 0) ? WTq : (z == 1) ? WTk : WTv;
    const int k0 = (xx & 15) << 6, n0 = (xx >> 4) << 6;
    const int c = threadIdx.x & 63, r0 = threadIdx.x >> 6;
#pragma unroll
    for (int i = 0; i < 16; ++i) {
      int r = (i << 2) + r0;
      tile[r][c] = W[(size_t)(k0 + r) * 1024 + n0 + c];
    }
    __syncthreads();
#pragma unroll
    for (int i = 0; i < 16; ++i) {
      int a = (i << 2) + r0;
      WT[(size_t)(n0 + a) * 1024 + k0 + c] = f2bf(tile[c][a]);
    }
  }
}

// ==== Q+K projections: tile 256x256, BK=64 8-phase, grid 256 (2 sel x 32 bm x 4 bn) ====
__global__ __launch_bounds__(512, 2) void qkproj_kernel(
    const short* __restrict__ Qc, const short* __restrict__ Vc,
    const short* __restrict__ WTq, const short* __restrict__ WTk,
    const float* __restrict__ bq, const float* __restrict__ bk,
    short* __restrict__ Qb, short* __restrict__ Kb) {
  __shared__ short lds[65536];  // 128 KB
  const int o = xswz(blockIdx.x, 256);
  const int sel = o >> 7, r = o & 127;
  const int bm = r >> 2, bn = r & 3;          // bm:[0,32) bn:[0,4)
  const short* A = sel ? Vc : Qc;
  const short* BT = sel ? WTk : WTq;
  const float* bias = sel ? bk : bq;
  short* O = sel ? Kb : Qb;
  const int m0 = bm * 256, n0 = bn * 256;
  f32x4 acc[8][4];
#pragma unroll
  for (int i = 0; i < 8; ++i)
#pragma unroll
    for (int j = 0; j < 4; ++j) acc[i][j] = (f32x4){0.f, 0.f, 0.f, 0.f};
  gemm64_core(A, BT, 1024, 1024, m0, n0, 16, lds, acc);
  const int tid = threadIdx.x;
  const int w = tid >> 6, l = tid & 63;
  const int wm = w >> 2, wn = w & 3, lr = l & 15, lg = l >> 4;
#pragma unroll
  for (int mf = 0; mf < 8; ++mf) {
    const int row0 = m0 + wm * 128 + mf * 16 + lg * 4;  // <= 8191
#pragma unroll
    for (int nf = 0; nf < 4; ++nf) {
      const int col = n0 + wn * 64 + nf * 16 + lr;      // <= n0+255 <= 1023
      const float bb = bias[col];
#pragma unroll
      for (int j = 0; j < 4; ++j)
        O[(size_t)(row0 + j) * 1024 + col] = f2bf(acc[mf][nf][j] + bb);
    }
  }
}

// ==== V projection -> VT[b][u][t]: tile 256x128, grid 256 (32 bm x 8 bn), ring-3 ====
__global__ __launch_bounds__(512, 2) void vproj_kernel(
    const short* __restrict__ Vc, const short* __restrict__ WTv,
    const float* __restrict__ bv, short* __restrict__ VT) {
  __shared__ short lds[36864];  // 72 KB: ring 3 x 12288; reused as 128x264 transpose buf
  const int o = xswz(blockIdx.x, 256);
  const int bm = o >> 3, bn = o & 7;
  const int m0 = bm * 256, n0 = bn * 128;     // m = t rows, n = u cols
  f32x4 acc[8][2];
#pragma unroll
  for (int i = 0; i < 8; ++i)
#pragma unroll
    for (int j = 0; j < 2; ++j) acc[i][j] = (f32x4){0.f, 0.f, 0.f, 0.f};
  gemm_core<1, 2, 3>(Vc, WTv, 1024, 1024, m0, n0, 32, lds, acc);
  const int tid = threadIdx.x;
  const int w = tid >> 6, l = tid & 63;
  const int wm = w >> 2, wn = w & 3, lr = l & 15, lg = l >> 4;
  __syncthreads();
  short* lt = lds;  // [u_local 0..127][t_local 0..255], stride 264
#pragma unroll
  for (int i = 0; i < 8; ++i) {
    const int tl = wm * 128 + (i >> 2) * 64 + (i & 3) * 16 + lg * 4;
#pragma unroll
    for (int nf = 0; nf < 2; ++nf) {
      const int ul = wn * 32 + nf * 16 + lr;
      const float bb = bv[n0 + ul];
      s16x4 pk;
#pragma unroll
      for (int j = 0; j < 4; ++j) pk[j] = f2bf(acc[i][nf][j] + bb);
      *(s16x4*)&lt[ul * 264 + tl] = pk;
    }
  }
  __syncthreads();
  const int b = m0 >> 11, t0 = m0 & 2047;
#pragma unroll
  for (int it = 0; it < 8; ++it) {
    const int cid = it * 512 + tid;
    const int u = cid >> 5, tc = cid & 31;
    s16x8 v8 = *(const s16x8*)&lt[u * 264 + tc * 8];
    *(s16x8*)(VT + ((size_t)b * 1024 + n0 + u) * 2048 + t0 + tc * 8) = v8;
  }
}

// ==== QK^T: scores=(Q.K)/32; tile 256x256 BK=64 8-phase, grid 256 (4 bt x 8 x 8) ====
__global__ __launch_bounds__(512, 2) void qkt_kernel(const short* __restrict__ Qb,
                                                     const short* __restrict__ Kb,
                                                     short* __restrict__ Sb) {
  __shared__ short lds[65536];  // 128 KB
  const int o = xswz(blockIdx.x, 256);
  const int bt = o >> 6, r = o & 63;
  const int bm = r >> 3, bn = r & 7;
  const short* A = Qb + (size_t)bt * 2097152;
  const short* B = Kb + (size_t)bt * 2097152;
  short* O = Sb + (size_t)bt * 4194304;
  const int m0 = bm * 256, n0 = bn * 256;
  f32x4 acc[8][4];
#pragma unroll
  for (int i = 0; i < 8; ++i)
#pragma unroll
    for (int j = 0; j < 4; ++j) acc[i][j] = (f32x4){0.f, 0.f, 0.f, 0.f};
  gemm64_core(A, B, 1024, 1024, m0, n0, 16, lds, acc);
  const int tid = threadIdx.x;
  const int w = tid >> 6, l = tid & 63;
  const int wm = w >> 2, wn = w & 3, lr = l & 15, lg = l >> 4;
#pragma unroll
  for (int mf = 0; mf < 8; ++mf) {
    const int row0 = m0 + wm * 128 + mf * 16 + lg * 4;  // <= 2047
#pragma unroll
    for (int nf = 0; nf < 4; ++nf) {
      const int col = n0 + wn * 64 + nf * 16 + lr;      // <= 2047
#pragma unroll
      for (int j = 0; j < 4; ++j)
        O[(size_t)(row0 + j) * 2048 + col] = f2bf(acc[mf][nf][j] * 0.03125f);
    }
  }
}

// ==== PV split-K: tile 256x256 BK=64 8-phase; grid 256 (2 kh x 4 bt x 8 bm x 4 bn) ====
// kh half covers 1024 score-cols -> nkt = 16. kh=0 -> Out, kh=1 -> Part; add folds.
__global__ __launch_bounds__(512, 2) void pv_kernel(const short* __restrict__ Sb,
                                                    const short* __restrict__ VT,
                                                    float* __restrict__ Out,
                                                    float* __restrict__ Part) {
  __shared__ short lds[65536];  // 128 KB
  const int o = xswz(blockIdx.x, 256);
  const int kh = o >> 7;                       // [0,2)
  const int bt = (o >> 5) & 3;                 // [0,4)
  const int bm = (o >> 2) & 7, bn = o & 3;     // bm:[0,8) bn:[0,4)
  const short* A = Sb + (size_t)bt * 4194304 + kh * 1024;
  const short* B = VT + (size_t)bt * 2097152 + kh * 1024;
  float* O = (kh ? Part : Out) + (size_t)bt * 2097152;
  const int m0 = bm * 256, n0 = bn * 256;
  f32x4 acc[8][4];
#pragma unroll
  for (int i = 0; i < 8; ++i)
#pragma unroll
    for (int j = 0; j < 4; ++j) acc[i][j] = (f32x4){0.f, 0.f, 0.f, 0.f};
  gemm64_core(A, B, 2048, 2048, m0, n0, 16, lds, acc);
  const int l = threadIdx.x & 63, w = threadIdx.x >> 6;
  const int wm = w >> 2, wn = w & 3, lr = l & 15, lg = l >> 4;
#pragma unroll
  for (int mf = 0; mf < 8; ++mf) {
    const int row0 = m0 + wm * 128 + mf * 16 + lg * 4;  // <= 2047
#pragma unroll
    for (int nf = 0; nf < 4; ++nf) {
      const int col = n0 + wn * 64 + nf * 16 + lr;      // <= 1023
#pragma unroll
      for (int j = 0; j < 4; ++j)
        O[(size_t)(row0 + j) * 1024 + col] = acc[mf][nf][j];
    }
  }
}

// ============ add: d_out += partial (8M floats, float4) ============
__global__ __launch_bounds__(256) void add_kernel(float* __restrict__ Out,
                                                  const float* __restrict__ Part) {
  const size_t i = ((size_t)blockIdx.x * 256 + threadIdx.x) * 4;
  f32x4 a = *(const f32x4*)(Out + i);
  f32x4 b = *(const f32x4*)(Part + i);
#pragma unroll
  for (int j = 0; j < 4; ++j) a[j] += b[j];
  *(f32x4*)(Out + i) = a;
}

// ============ Row softmax, in-place on bf16 scores [B*S rows][2048] ============
__global__ __launch_bounds__(256) void softmax_kernel(short* __restrict__ Sb) {
  const size_t row = blockIdx.x;
  short* p = Sb + row * 2048;
  const int tid = threadIdx.x;
  const int w = tid >> 6, l = tid & 63;
  s16x8 v = *(const s16x8*)(p + tid * 8);
  float f[8];
#pragma unroll
  for (int j = 0; j < 8; ++j) f[j] = bf2f(v[j]);
  float m = f[0];
#pragma unroll
  for (int j = 1; j < 8; ++j) m = fmaxf(m, f[j]);
#pragma unroll
  for (int o = 32; o > 0; o >>= 1) m = fmaxf(m, __shfl_xor(m, o, 64));
  __shared__ float redm[4], reds[4];
  if (l == 0) redm[w] = m;
  __syncthreads();
  m = fmaxf(fmaxf(redm[0], redm[1]), fmaxf(redm[2], redm[3]));
  float s = 0.f;
#pragma unroll
  for (int j = 0; j < 8; ++j) { f[j] = __expf(f[j] - m); s += f[j]; }
#pragma unroll
  for (int o = 32; o > 0; o >>= 1) s += __shfl_xor(s, o, 64);
  if (l == 0) reds[w] = s;
  __syncthreads();
  s = reds[0] + reds[1] + reds[2] + reds[3];
  const float inv = 1.f / s;
  s16x8 o8;
#pragma unroll
  for (int j = 0; j < 8; ++j) o8[j] = f2bf(f[j] * inv);
  *(s16x8*)(p + tid * 8) = o8;
}

// ============ launch ============
extern "C" void kernel_launch(void* const* d_in, const int* in_sizes, int n_in,
                              void* d_out, int out_size, void* d_ws, size_t ws_size,
                              hipStream_t stream) {
  const float* query = (const float*)d_in[0];
  const float* value = (const float*)d_in[1];
  const float* Wq = (const float*)d_in[2];
  const float* bq = (const float*)d_in[3];
  const float* Wk = (const float*)d_in[4];
  const float* bk = (const float*)d_in[5];
  const float* Wv = (const float*)d_in[6];
  const float* bv = (const float*)d_in[7];

  // Workspace layout (86 MB total):
  //  0: WTq(2M) 2M: WTk(2M) 4M: WTv(2M)
  //  6M: region X (32MB): Qc@6M(16M), Vc@22M(16M); later Sb@6M(32MB) [disjoint lifetimes]
  //  38M: Qb(16M) 54M: Kb(16M) -- dead after qkt; reused as Part@38M(32MB fp32)
  //  70M: VT(16M)
  char* ws = (char*)d_ws;
  short* WTq = (short*)(ws);
  short* WTk = (short*)(ws + ((size_t)2 << 20));
  short* WTv = (short*)(ws + ((size_t)4 << 20));
  short* Qc  = (short*)(ws + ((size_t)6 << 20));
  short* Vc  = (short*)(ws + ((size_t)22 << 20));
  short* Sb  = (short*)(ws + ((size_t)6 << 20));
  short* Qb  = (short*)(ws + ((size_t)38 << 20));
  short* Kb  = (short*)(ws + ((size_t)54 << 20));
  float* Part = (float*)(ws + ((size_t)38 << 20));
  short* VT  = (short*)(ws + ((size_t)70 << 20));

  prep_kernel<<<dim3(8960), 256, 0, stream>>>(query, value, Wq, Wk, Wv, Qc, Vc, WTq, WTk, WTv);

  qkproj_kernel<<<dim3(256), 512, 0, stream>>>(Qc, Vc, WTq, WTk, bq, bk, Qb, Kb);
  vproj_kernel<<<dim3(256), 512, 0, stream>>>(Vc, WTv, bv, VT);

  // scores[b][s][t] = (Q.K)/32
  qkt_kernel<<<dim3(256), 512, 0, stream>>>(Qb, Kb, Sb);

  softmax_kernel<<<dim3(8192), 256, 0, stream>>>(Sb);

  // out[b][s][u] = P @ V, split-K=2 (Qb/Kb dead -> Part reuses their region)
  pv_kernel<<<dim3(256), 512, 0, stream>>>(Sb, VT, (float*)d_out, Part);
  add_kernel<<<dim3(8192), 256, 0, stream>>>((float*)d_out, Part);
}

// Round 11
// 190.495 us; speedup vs baseline: 1.0355x; 1.0002x over previous
//
#include <hip/hip_runtime.h>
#include <hip/hip_bf16.h>
#include <stdint.h>

#define DEVINL __device__ __forceinline__

typedef __attribute__((ext_vector_type(4))) float f32x4;
typedef __attribute__((ext_vector_type(8))) __bf16 bfv8;
typedef __attribute__((ext_vector_type(8))) short s16x8;
typedef __attribute__((ext_vector_type(4))) short s16x4;

// ---- helpers ----
DEVINL short f2bf(float f) {  // fp32 -> bf16 bits, RTNE
  union { float f; unsigned u; } v; v.f = f;
  unsigned r = v.u + 0x7FFFu + ((v.u >> 16) & 1u);
  return (short)(r >> 16);
}
DEVINL float bf2f(short h) {
  union { unsigned u; float f; } v; v.u = ((unsigned)(unsigned short)h) << 16;
  return v.f;
}
DEVINL void gload_lds16(const void* g, void* l) {
  // 16B direct global->LDS. LDS dest = wave-uniform base + lane*16.
  __builtin_amdgcn_global_load_lds((__attribute__((address_space(1))) unsigned*)(g),
                                   (__attribute__((address_space(3))) unsigned*)(l),
                                   16, 0, 0);
}
#define S_BARRIER() __builtin_amdgcn_s_barrier()
#define MEMORD() asm volatile("" ::: "memory")
template <int N> DEVINL void vmwaitc() {
  asm volatile("s_waitcnt vmcnt(%0)" :: "i"(N) : "memory");
}
// bijective XCD swizzle (n % 8 == 0): consecutive output slots cluster per XCD
DEVINL int xswz(int p, int n) { return (p & 7) * (n >> 3) + (p >> 3); }

// ========== 256x256 tile, BK=64, COUNTED-VMCNT core (A ring-3 + B single-buf) ==========
// 512 threads = 8 waves (2M x 4N); wave tile 128x64; acc[8][4] of 16x16 frags.
// LDS (shorts): A ring slots 0/1/2 @ {0,16384,32768} (32 KB each, [256][64] swizzled);
//               B buffer @ 49152 (32 KB). Total 128 KB.
// Lifetimes: B(t) is read ONLY in phase 0 (into regs) -> dead after ph0 trailing barrier
//   -> B(t+1) staged at ph1 into the SAME buffer (WAR-free). A(t) is read all 4 phases
//   -> ring-3: A(t+2) staged at ph2 into ring[(t+2)%3], untouched by tiles t, t+1.
// Issue order: ... B(t+1)@ph1, A(t+2)@ph2 -> at ph3 (after MFMA q3) ONE vmcnt(4): leaves
//   A(t+2)'s 4 loads in flight, guarantees older A(t+1), B(t+1) landed; trailing barrier
//   publishes cross-wave. NEVER vmcnt(0) mid-loop (T4; m218: drain-0 ~= 1-phase).
// RAW: A(t+1) covered by tile t's vmcnt(4) (issued t-1 ph2, older than B(t+1)); B(t+1)
//   covered directly. WAR: proven by lifetimes above. Tail (kt+2>=nkt): vmcnt(0).
// Swizzle (128B rows, 8 chunks): storage chunk = logical chunk ^ (row&7); inverse-swizzled
//   GLOBAL source + swizzled ds_read. Verified 0 bank conflicts (r10).
DEVINL void gemm64_core(const short* __restrict__ Ag, const short* __restrict__ Bg,
                        int lda, int ldb, int m0, int n0, int nkt,
                        short* lds, f32x4 (&acc)[8][4]) {
  const int tid = threadIdx.x;
  const int w = tid >> 6, l = tid & 63;
  const int wm = w >> 2, wn = w & 3;
  const int lr = l & 15, lg = l >> 4;
  // staging: per gload, wave w covers rows 8w..8w+7 of a 64-row quarter (lane l -> +l>>3)
  const int srow = 8 * w + (l >> 3);
  const int scol = (((l & 7) ^ ((l >> 3) & 7)) << 3);  // inverse-swizzled source col
  const int dW = w * 512;                              // wave-uniform dest offset (shorts)
  // fragment reads: chunk = (ks*4+lg) ^ (row&7), row&7 == lr&7
  const int xk0 = ((lg ^ (lr & 7)) << 3);
  const int xk1 = (((4 + lg) ^ (lr & 7)) << 3);
  const int aoff = (wm * 128 + lr) * 64;               // + mf*1024 + xk (within A slot)
  const int boff = 49152 + (wn * 64 + lr) * 64;        // + nf*1024 + xk

#define SG_A4(t, ring) { short* S_ = lds + (ring) * 16384;                                \
    _Pragma("unroll")                                                                     \
    for (int q_ = 0; q_ < 4; ++q_)                                                        \
      gload_lds16(Ag + (size_t)(m0 + 64 * q_ + srow) * lda + (t) * 64 + scol,             \
                  S_ + q_ * 4096 + dW); }
#define SG_B4(t) { short* S_ = lds + 49152;                                               \
    _Pragma("unroll")                                                                     \
    for (int q_ = 0; q_ < 4; ++q_)                                                        \
      gload_lds16(Bg + (size_t)(n0 + 64 * q_ + srow) * ldb + (t) * 64 + scol,             \
                  S_ + q_ * 4096 + dW); }
#define MFMA_QUAD(M0, M1)                                                                 \
    _Pragma("unroll")                                                                     \
    for (int nf = 0; nf < 4; ++nf) {                                                      \
      acc[M0][nf] = __builtin_amdgcn_mfma_f32_16x16x32_bf16(a00, br[nf][0], acc[M0][nf], 0, 0, 0); \
      acc[M0][nf] = __builtin_amdgcn_mfma_f32_16x16x32_bf16(a01, br[nf][1], acc[M0][nf], 0, 0, 0); \
      acc[M1][nf] = __builtin_amdgcn_mfma_f32_16x16x32_bf16(a10, br[nf][0], acc[M1][nf], 0, 0, 0); \
      acc[M1][nf] = __builtin_amdgcn_mfma_f32_16x16x32_bf16(a11, br[nf][1], acc[M1][nf], 0, 0, 0); \
    }

  // ---- prologue: A(0)->r0, B(0), A(1)->r1 (A(1) last!); vmcnt(4) leaves A(1) in flight ----
  SG_A4(0, 0); SG_B4(0);
  if (nkt > 1) SG_A4(1, 1);
  if (nkt > 1) vmwaitc<4>(); else vmwaitc<0>();
  S_BARRIER(); MEMORD();

  int ra = 0;  // ring index of tile kt
#pragma unroll 1
  for (int kt = 0; kt < nkt; ++kt) {
    const short* S = lds + ra * 16384;
    bfv8 br[4][2];
    // ---------- phase 0: B(all) + A(q0) reads ----------
#pragma unroll
    for (int nf = 0; nf < 4; ++nf) {
      br[nf][0] = *(const bfv8*)(lds + boff + nf * 1024 + xk0);
      br[nf][1] = *(const bfv8*)(lds + boff + nf * 1024 + xk1);
    }
    bfv8 a00 = *(const bfv8*)(S + aoff + 0 * 1024 + xk0);
    bfv8 a01 = *(const bfv8*)(S + aoff + 0 * 1024 + xk1);
    bfv8 a10 = *(const bfv8*)(S + aoff + 1 * 1024 + xk0);
    bfv8 a11 = *(const bfv8*)(S + aoff + 1 * 1024 + xk1);
    S_BARRIER();
    __builtin_amdgcn_s_setprio(1);
    MFMA_QUAD(0, 1);
    __builtin_amdgcn_s_setprio(0);
    S_BARRIER(); MEMORD();
    // ---------- phase 1: A(q1) reads | issue B(kt+1) (B-buf dead since ph0 barrier) ----------
    a00 = *(const bfv8*)(S + aoff + 2 * 1024 + xk0);
    a01 = *(const bfv8*)(S + aoff + 2 * 1024 + xk1);
    a10 = *(const bfv8*)(S + aoff + 3 * 1024 + xk0);
    a11 = *(const bfv8*)(S + aoff + 3 * 1024 + xk1);
    if (kt + 1 < nkt) SG_B4(kt + 1);
    S_BARRIER();
    __builtin_amdgcn_s_setprio(1);
    MFMA_QUAD(2, 3);
    __builtin_amdgcn_s_setprio(0);
    S_BARRIER(); MEMORD();
    // ---------- phase 2: A(q2) reads | issue A(kt+2) -> ring[(kt+2)%3] ----------
    a00 = *(const bfv8*)(S + aoff + 4 * 1024 + xk0);
    a01 = *(const bfv8*)(S + aoff + 4 * 1024 + xk1);
    a10 = *(const bfv8*)(S + aoff + 5 * 1024 + xk0);
    a11 = *(const bfv8*)(S + aoff + 5 * 1024 + xk1);
    if (kt + 2 < nkt) {
      int r2 = ra + 2; if (r2 >= 3) r2 -= 3;
      SG_A4(kt + 2, r2);
    }
    S_BARRIER();
    __builtin_amdgcn_s_setprio(1);
    MFMA_QUAD(4, 5);
    __builtin_amdgcn_s_setprio(0);
    S_BARRIER(); MEMORD();
    // ---------- phase 3: A(q3) reads | MFMA | COUNTED vmcnt | publish ----------
    a00 = *(const bfv8*)(S + aoff + 6 * 1024 + xk0);
    a01 = *(const bfv8*)(S + aoff + 6 * 1024 + xk1);
    a10 = *(const bfv8*)(S + aoff + 7 * 1024 + xk0);
    a11 = *(const bfv8*)(S + aoff + 7 * 1024 + xk1);
    S_BARRIER();
    __builtin_amdgcn_s_setprio(1);
    MFMA_QUAD(6, 7);
    __builtin_amdgcn_s_setprio(0);
    if (kt + 2 < nkt) vmwaitc<4>();       // A(kt+1),B(kt+1) landed; A(kt+2) stays in flight
    else if (kt + 1 < nkt) vmwaitc<0>();  // tail: drain for last tile
    S_BARRIER(); MEMORD();
    ra = (ra + 1 == 3) ? 0 : ra + 1;
  }
#undef SG_A4
#undef SG_B4
#undef MFMA_QUAD
}

// ======== legacy 256x128 ring-3 core (proven r6-r9) — kept for vproj ========
template <int BU, int NF, int RING>
DEVINL void gemm_core(const short* __restrict__ Ag, const short* __restrict__ Bg,
                      int lda, int ldb, int m0, int n0, int nkt,
                      short* lds, f32x4 (&acc)[8][NF]) {
  constexpr int U = 2 + BU;
  constexpr int SLOT = 8192 + BU * 4096;
  const int tid = threadIdx.x;
  const int w = tid >> 6, l = tid & 63;
  const int wm = w >> 2, wn = w & 3;
  const int lr = l & 15, lg = l >> 4;
  const int stg_row = w * 16 + (l >> 2);
  const int stg_col = (((l & 3) ^ ((l >> 3) & 3)) << 3);
  const int ck = ((lg ^ ((lr >> 1) & 3)) << 3);
  const int aro = (wm * 128 + lr) * 32 + ck;
  const int bro = 8192 + (wn * (NF * 16) + lr) * 32 + ck;
  const int dW = w * 512;
#define STAGE_A(t) { short* S_ = lds + ((t) % RING) * SLOT;                                \
    gload_lds16(Ag + (size_t)(m0 + stg_row) * lda + (t) * 32 + stg_col, S_ + dW);          \
    gload_lds16(Ag + (size_t)(m0 + 128 + stg_row) * lda + (t) * 32 + stg_col,              \
                S_ + 4096 + dW); }
#define STAGE_B(t) { short* S_ = lds + ((t) % RING) * SLOT;                                \
    _Pragma("unroll")                                                                      \
    for (int u_ = 0; u_ < BU; ++u_)                                                        \
      gload_lds16(Bg + (size_t)(n0 + u_ * 128 + stg_row) * ldb + (t) * 32 + stg_col,       \
                  S_ + 8192 + u_ * 4096 + dW); }
#pragma unroll
  for (int t = 0; t < RING - 1; ++t) { STAGE_A(t); STAGE_B(t); }
  vmwaitc<(RING - 2) * U>(); S_BARRIER(); MEMORD();
  bfv8 aA[4], aB[4], bA[NF], bB[NF];
  {
    const short* Sp = lds;
#pragma unroll
    for (int mf = 0; mf < 4; ++mf) aA[mf] = *(const bfv8*)(Sp + aro + mf * 512);
#pragma unroll
    for (int nf = 0; nf < NF; ++nf) bA[nf] = *(const bfv8*)(Sp + bro + nf * 512);
  }
#pragma unroll 1
  for (int kt = 0; kt < nkt; kt += 2) {
    const short* S1 = lds + ((kt + 1) % RING) * SLOT;
    const short* S2 = lds + ((kt + 2) % RING) * SLOT;
    const short* S0 = lds + (kt % RING) * SLOT;
    if (kt + 2 < nkt) STAGE_A(kt + 2);
#pragma unroll
    for (int mf = 0; mf < 4; ++mf) aB[mf] = *(const bfv8*)(S0 + aro + 2048 + mf * 512);
#pragma unroll
    for (int mf = 0; mf < 4; ++mf)
#pragma unroll
      for (int nf = 0; nf < NF; ++nf)
        acc[mf][nf] = __builtin_amdgcn_mfma_f32_16x16x32_bf16(aA[mf], bA[nf], acc[mf][nf], 0, 0, 0);
    if (kt + 2 < nkt) vmwaitc<2>(); else vmwaitc<0>();
    S_BARRIER(); MEMORD();
    if (kt + 2 < nkt) STAGE_B(kt + 2);
#pragma unroll
    for (int mf = 0; mf < 4; ++mf) aA[mf] = *(const bfv8*)(S1 + aro + mf * 512);
#pragma unroll
    for (int nf = 0; nf < NF; ++nf) bB[nf] = *(const bfv8*)(S1 + bro + nf * 512);
#pragma unroll
    for (int mf = 0; mf < 4; ++mf)
#pragma unroll
      for (int nf = 0; nf < NF; ++nf)
        acc[4 + mf][nf] = __builtin_amdgcn_mfma_f32_16x16x32_bf16(aB[mf], bA[nf], acc[4 + mf][nf], 0, 0, 0);
    S_BARRIER(); MEMORD();
    if (kt + 3 < nkt) STAGE_A(kt + 3);
#pragma unroll
    for (int mf = 0; mf < 4; ++mf) aB[mf] = *(const bfv8*)(S1 + aro + 2048 + mf * 512);
#pragma unroll
    for (int mf = 0; mf < 4; ++mf)
#pragma unroll
      for (int nf = 0; nf < NF; ++nf)
        acc[mf][nf] = __builtin_amdgcn_mfma_f32_16x16x32_bf16(aA[mf], bB[nf], acc[mf][nf], 0, 0, 0);
    if (kt + 3 < nkt) vmwaitc<2>(); else vmwaitc<0>();
    S_BARRIER(); MEMORD();
    if (kt + 3 < nkt) STAGE_B(kt + 3);
    if (kt + 2 < nkt) {
#pragma unroll
      for (int mf = 0; mf < 4; ++mf) aA[mf] = *(const bfv8*)(S2 + aro + mf * 512);
#pragma unroll
      for (int nf = 0; nf < NF; ++nf) bA[nf] = *(const bfv8*)(S2 + bro + nf * 512);
    }
#pragma unroll
    for (int mf = 0; mf < 4; ++mf)
#pragma unroll
      for (int nf = 0; nf < NF; ++nf)
        acc[4 + mf][nf] = __builtin_amdgcn_mfma_f32_16x16x32_bf16(aB[mf], bB[nf], acc[4 + mf][nf], 0, 0, 0);
    S_BARRIER(); MEMORD();
  }
#undef STAGE_A
#undef STAGE_B
}

// ============ prep: cast fp32->bf16 (Q,V) fused with W transpose+cast ============
__global__ __launch_bounds__(256) void prep_kernel(
    const float* __restrict__ q, const float* __restrict__ v,
    const float* __restrict__ Wq, const float* __restrict__ Wk, const float* __restrict__ Wv,
    short* __restrict__ Qc, short* __restrict__ Vc,
    short* __restrict__ WTq, short* __restrict__ WTk, short* __restrict__ WTv) {
  __shared__ float tile[64][65];
  const int bx = blockIdx.x;
  if (bx < 8192) {
    const float* src = (bx < 4096) ? q : v;
    short* dst = (bx < 4096) ? Qc : Vc;
    const size_t i = ((size_t)(bx & 4095) * 256 + threadIdx.x) * 8;
    f32x4 x0 = *(const f32x4*)(src + i);
    f32x4 x1 = *(const f32x4*)(src + i + 4);
    s16x8 o;
#pragma unroll
    for (int j = 0; j < 4; ++j) { o[j] = f2bf(x0[j]); o[4 + j] = f2bf(x1[j]); }
    *(s16x8*)(dst + i) = o;
  } else {
    const int z = (bx - 8192) >> 8, xx = (bx - 8192) & 255;
    const float* W = (z == 0) ? Wq : (z == 1) ? Wk : Wv;
    short* WT = (z == 0) ? WTq : (z == 1) ? WTk : WTv;
    const int k0 = (xx & 15) << 6, n0 = (xx >> 4) << 6;
    const int c = threadIdx.x & 63, r0 = threadIdx.x >> 6;
#pragma unroll
    for (int i = 0; i < 16; ++i) {
      int r = (i << 2) + r0;
      tile[r][c] = W[(size_t)(k0 + r) * 1024 + n0 + c];
    }
    __syncthreads();
#pragma unroll
    for (int i = 0; i < 16; ++i) {
      int a = (i << 2) + r0;
      WT[(size_t)(n0 + a) * 1024 + k0 + c] = f2bf(tile[c][a]);
    }
  }
}

// ==== Q+K projections: tile 256x256, BK=64 counted core, grid 256 (2 sel x 32 bm x 4 bn) ====
__global__ __launch_bounds__(512, 2) void qkproj_kernel(
    const short* __restrict__ Qc, const short* __restrict__ Vc,
    const short* __restrict__ WTq, const short* __restrict__ WTk,
    const float* __restrict__ bq, const float* __restrict__ bk,
    short* __restrict__ Qb, short* __restrict__ Kb) {
  __shared__ short lds[65536];  // 128 KB
  const int o = xswz(blockIdx.x, 256);
  const int sel = o >> 7, r = o & 127;
  const int bm = r >> 2, bn = r & 3;          // bm:[0,32) bn:[0,4)
  const short* A = sel ? Vc : Qc;
  const short* BT = sel ? WTk : WTq;
  const float* bias = sel ? bk : bq;
  short* O = sel ? Kb : Qb;
  const int m0 = bm * 256, n0 = bn * 256;
  f32x4 acc[8][4];
#pragma unroll
  for (int i = 0; i < 8; ++i)
#pragma unroll
    for (int j = 0; j < 4; ++j) acc[i][j] = (f32x4){0.f, 0.f, 0.f, 0.f};
  gemm64_core(A, BT, 1024, 1024, m0, n0, 16, lds, acc);
  const int tid = threadIdx.x;
  const int w = tid >> 6, l = tid & 63;
  const int wm = w >> 2, wn = w & 3, lr = l & 15, lg = l >> 4;
#pragma unroll
  for (int mf = 0; mf < 8; ++mf) {
    const int row0 = m0 + wm * 128 + mf * 16 + lg * 4;  // <= 8191
#pragma unroll
    for (int nf = 0; nf < 4; ++nf) {
      const int col = n0 + wn * 64 + nf * 16 + lr;      // <= 1023
      const float bb = bias[col];
#pragma unroll
      for (int j = 0; j < 4; ++j)
        O[(size_t)(row0 + j) * 1024 + col] = f2bf(acc[mf][nf][j] + bb);
    }
  }
}

// ==== V projection -> VT[b][u][t]: tile 256x128, grid 256 (32 bm x 8 bn), ring-3 ====
__global__ __launch_bounds__(512, 2) void vproj_kernel(
    const short* __restrict__ Vc, const short* __restrict__ WTv,
    const float* __restrict__ bv, short* __restrict__ VT) {
  __shared__ short lds[36864];  // 72 KB: ring 3 x 12288; reused as 128x264 transpose buf
  const int o = xswz(blockIdx.x, 256);
  const int bm = o >> 3, bn = o & 7;
  const int m0 = bm * 256, n0 = bn * 128;     // m = t rows, n = u cols
  f32x4 acc[8][2];
#pragma unroll
  for (int i = 0; i < 8; ++i)
#pragma unroll
    for (int j = 0; j < 2; ++j) acc[i][j] = (f32x4){0.f, 0.f, 0.f, 0.f};
  gemm_core<1, 2, 3>(Vc, WTv, 1024, 1024, m0, n0, 32, lds, acc);
  const int tid = threadIdx.x;
  const int w = tid >> 6, l = tid & 63;
  const int wm = w >> 2, wn = w & 3, lr = l & 15, lg = l >> 4;
  __syncthreads();
  short* lt = lds;  // [u_local 0..127][t_local 0..255], stride 264
#pragma unroll
  for (int i = 0; i < 8; ++i) {
    const int tl = wm * 128 + (i >> 2) * 64 + (i & 3) * 16 + lg * 4;
#pragma unroll
    for (int nf = 0; nf < 2; ++nf) {
      const int ul = wn * 32 + nf * 16 + lr;
      const float bb = bv[n0 + ul];
      s16x4 pk;
#pragma unroll
      for (int j = 0; j < 4; ++j) pk[j] = f2bf(acc[i][nf][j] + bb);
      *(s16x4*)&lt[ul * 264 + tl] = pk;
    }
  }
  __syncthreads();
  const int b = m0 >> 11, t0 = m0 & 2047;
#pragma unroll
  for (int it = 0; it < 8; ++it) {
    const int cid = it * 512 + tid;
    const int u = cid >> 5, tc = cid & 31;
    s16x8 v8 = *(const s16x8*)&lt[u * 264 + tc * 8];
    *(s16x8*)(VT + ((size_t)b * 1024 + n0 + u) * 2048 + t0 + tc * 8) = v8;
  }
}

// ==== QK^T: scores=(Q.K)/32; tile 256x256 counted core, grid 256 (4 bt x 8 x 8) ====
__global__ __launch_bounds__(512, 2) void qkt_kernel(const short* __restrict__ Qb,
                                                     const short* __restrict__ Kb,
                                                     short* __restrict__ Sb) {
  __shared__ short lds[65536];  // 128 KB
  const int o = xswz(blockIdx.x, 256);
  const int bt = o >> 6, r = o & 63;
  const int bm = r >> 3, bn = r & 7;
  const short* A = Qb + (size_t)bt * 2097152;
  const short* B = Kb + (size_t)bt * 2097152;
  short* O = Sb + (size_t)bt * 4194304;
  const int m0 = bm * 256, n0 = bn * 256;
  f32x4 acc[8][4];
#pragma unroll
  for (int i = 0; i < 8; ++i)
#pragma unroll
    for (int j = 0; j < 4; ++j) acc[i][j] = (f32x4){0.f, 0.f, 0.f, 0.f};
  gemm64_core(A, B, 1024, 1024, m0, n0, 16, lds, acc);
  const int tid = threadIdx.x;
  const int w = tid >> 6, l = tid & 63;
  const int wm = w >> 2, wn = w & 3, lr = l & 15, lg = l >> 4;
#pragma unroll
  for (int mf = 0; mf < 8; ++mf) {
    const int row0 = m0 + wm * 128 + mf * 16 + lg * 4;  // <= 2047
#pragma unroll
    for (int nf = 0; nf < 4; ++nf) {
      const int col = n0 + wn * 64 + nf * 16 + lr;      // <= 2047
#pragma unroll
      for (int j = 0; j < 4; ++j)
        O[(size_t)(row0 + j) * 2048 + col] = f2bf(acc[mf][nf][j] * 0.03125f);
    }
  }
}

// ==== PV split-K: tile 256x256 counted core; grid 256 (2 kh x 4 bt x 8 bm x 4 bn) ====
// Each kh half covers 1024 score-cols -> nkt = 16. kh=0 -> Out, kh=1 -> Part; add folds.
__global__ __launch_bounds__(512, 2) void pv_kernel(const short* __restrict__ Sb,
                                                    const short* __restrict__ VT,
                                                    float* __restrict__ Out,
                                                    float* __restrict__ Part) {
  __shared__ short lds[65536];  // 128 KB
  const int o = xswz(blockIdx.x, 256);
  const int kh = o >> 7;                       // [0,2)
  const int bt = (o >> 5) & 3;                 // [0,4)
  const int bm = (o >> 2) & 7, bn = o & 3;     // bm:[0,8) bn:[0,4)
  const short* A = Sb + (size_t)bt * 4194304 + kh * 1024;
  const short* B = VT + (size_t)bt * 2097152 + kh * 1024;
  float* O = (kh ? Part : Out) + (size_t)bt * 2097152;
  const int m0 = bm * 256, n0 = bn * 256;
  f32x4 acc[8][4];
#pragma unroll
  for (int i = 0; i < 8; ++i)
#pragma unroll
    for (int j = 0; j < 4; ++j) acc[i][j] = (f32x4){0.f, 0.f, 0.f, 0.f};
  gemm64_core(A, B, 2048, 2048, m0, n0, 16, lds, acc);
  const int l = threadIdx.x & 63, w = threadIdx.x >> 6;
  const int wm = w >> 2, wn = w & 3, lr = l & 15, lg = l >> 4;
#pragma unroll
  for (int mf = 0; mf < 8; ++mf) {
    const int row0 = m0 + wm * 128 + mf * 16 + lg * 4;  // <= 2047
#pragma unroll
    for (int nf = 0; nf < 4; ++nf) {
      const int col = n0 + wn * 64 + nf * 16 + lr;      // <= 1023
#pragma unroll
      for (int j = 0; j < 4; ++j)
        O[(size_t)(row0 + j) * 1024 + col] = acc[mf][nf][j];
    }
  }
}

// ============ add: d_out += partial (8M floats, float4) ============
__global__ __launch_bounds__(256) void add_kernel(float* __restrict__ Out,
                                                  const float* __restrict__ Part) {
  const size_t i = ((size_t)blockIdx.x * 256 + threadIdx.x) * 4;
  f32x4 a = *(const f32x4*)(Out + i);
  f32x4 b = *(const f32x4*)(Part + i);
#pragma unroll
  for (int j = 0; j < 4; ++j) a[j] += b[j];
  *(f32x4*)(Out + i) = a;
}

// ============ Row softmax, in-place on bf16 scores [B*S rows][2048] ============
__global__ __launch_bounds__(256) void softmax_kernel(short* __restrict__ Sb) {
  const size_t row = blockIdx.x;
  short* p = Sb + row * 2048;
  const int tid = threadIdx.x;
  const int w = tid >> 6, l = tid & 63;
  s16x8 v = *(const s16x8*)(p + tid * 8);
  float f[8];
#pragma unroll
  for (int j = 0; j < 8; ++j) f[j] = bf2f(v[j]);
  float m = f[0];
#pragma unroll
  for (int j = 1; j < 8; ++j) m = fmaxf(m, f[j]);
#pragma unroll
  for (int o = 32; o > 0; o >>= 1) m = fmaxf(m, __shfl_xor(m, o, 64));
  __shared__ float redm[4], reds[4];
  if (l == 0) redm[w] = m;
  __syncthreads();
  m = fmaxf(fmaxf(redm[0], redm[1]), fmaxf(redm[2], redm[3]));
  float s = 0.f;
#pragma unroll
  for (int j = 0; j < 8; ++j) { f[j] = __expf(f[j] - m); s += f[j]; }
#pragma unroll
  for (int o = 32; o > 0; o >>= 1) s += __shfl_xor(s, o, 64);
  if (l == 0) reds[w] = s;
  __syncthreads();
  s = reds[0] + reds[1] + reds[2] + reds[3];
  const float inv = 1.f / s;
  s16x8 o8;
#pragma unroll
  for (int j = 0; j < 8; ++j) o8[j] = f2bf(f[j] * inv);
  *(s16x8*)(p + tid * 8) = o8;
}

// ============ launch ============
extern "C" void kernel_launch(void* const* d_in, const int* in_sizes, int n_in,
                              void* d_out, int out_size, void* d_ws, size_t ws_size,
                              hipStream_t stream) {
  const float* query = (const float*)d_in[0];
  const float* value = (const float*)d_in[1];
  const float* Wq = (const float*)d_in[2];
  const float* bq = (const float*)d_in[3];
  const float* Wk = (const float*)d_in[4];
  const float* bk = (const float*)d_in[5];
  const float* Wv = (const float*)d_in[6];
  const float* bv = (const float*)d_in[7];

  // Workspace layout (86 MB total):
  //  0: WTq(2M) 2M: WTk(2M) 4M: WTv(2M)
  //  6M: region X (32MB): Qc@6M(16M), Vc@22M(16M); later Sb@6M(32MB) [disjoint lifetimes]
  //  38M: Qb(16M) 54M: Kb(16M) -- dead after qkt; reused as Part@38M(32MB fp32)
  //  70M: VT(16M)
  char* ws = (char*)d_ws;
  short* WTq = (short*)(ws);
  short* WTk = (short*)(ws + ((size_t)2 << 20));
  short* WTv = (short*)(ws + ((size_t)4 << 20));
  short* Qc  = (short*)(ws + ((size_t)6 << 20));
  short* Vc  = (short*)(ws + ((size_t)22 << 20));
  short* Sb  = (short*)(ws + ((size_t)6 << 20));
  short* Qb  = (short*)(ws + ((size_t)38 << 20));
  short* Kb  = (short*)(ws + ((size_t)54 << 20));
  float* Part = (float*)(ws + ((size_t)38 << 20));
  short* VT  = (short*)(ws + ((size_t)70 << 20));

  prep_kernel<<<dim3(8960), 256, 0, stream>>>(query, value, Wq, Wk, Wv, Qc, Vc, WTq, WTk, WTv);

  qkproj_kernel<<<dim3(256), 512, 0, stream>>>(Qc, Vc, WTq, WTk, bq, bk, Qb, Kb);
  vproj_kernel<<<dim3(256), 512, 0, stream>>>(Vc, WTv, bv, VT);

  // scores[b][s][t] = (Q.K)/32
  qkt_kernel<<<dim3(256), 512, 0, stream>>>(Qb, Kb, Sb);

  softmax_kernel<<<dim3(8192), 256, 0, stream>>>(Sb);

  // out[b][s][u] = P @ V, split-K=2 (Qb/Kb dead -> Part reuses their region)
  pv_kernel<<<dim3(256), 512, 0, stream>>>(Sb, VT, (float*)d_out, Part);
  add_kernel<<<dim3(8192), 256, 0, stream>>>((float*)d_out, Part);
}